// Round 1
// baseline (18.147 us; speedup 1.0000x reference)
//
#include <hip/hip_runtime.h>

// RerankLoss: margin-ranking hinge over all pos-neg pairs per row.
// scores: [B, L] f32, labels: [B, L] i32 in {0,1}; output: scalar f32.
// out = (1/B) * sum_b [ sum_{i pos, j neg} relu(1 - (s_i - s_j)) / (n_pos*n_neg) ]

constexpr int L = 200;
constexpr float MARGIN = 1.0f;

__global__ __launch_bounds__(256) void rerank_per_sample(
    const float* __restrict__ scores,
    const int*   __restrict__ labels,
    float*       __restrict__ per_sample)
{
    __shared__ float posv[L + 8];
    __shared__ float negv[L + 8];
    __shared__ int   cnts[2];   // [0] = n_neg, [1] = n_pos
    __shared__ float wsum[4];

    const int b   = blockIdx.x;
    const int tid = threadIdx.x;

    if (tid < 2) cnts[tid] = 0;
    __syncthreads();

    const float* s  = scores + (long)b * L;
    const int*   lb = labels + (long)b * L;

    if (tid < L) {
        float v = s[tid];
        int   l = lb[tid];
        int   k = atomicAdd(&cnts[l], 1);
        if (l) posv[k] = v;
        else   negv[k] = v;
    }
    __syncthreads();

    const int npos = cnts[1];
    const int nneg = cnts[0];
    const int nneg4 = (nneg + 3) & ~3;
    // pad negatives so float4 inner loop reads full quads; relu(c - 3e38) = 0
    if (tid < nneg4 - nneg) negv[nneg + tid] = -3.0e38f;
    __syncthreads();

    float acc = 0.0f;
    const float4* nv = (const float4*)negv;
    for (int i = tid; i < npos; i += 256) {
        const float c = MARGIN - posv[i];
        float a0 = 0.f, a1 = 0.f, a2 = 0.f, a3 = 0.f;
        const int nq = nneg4 >> 2;
        for (int j = 0; j < nq; ++j) {
            float4 n = nv[j];               // LDS broadcast (same addr all lanes)
            a0 += fmaxf(c + n.x, 0.0f);
            a1 += fmaxf(c + n.y, 0.0f);
            a2 += fmaxf(c + n.z, 0.0f);
            a3 += fmaxf(c + n.w, 0.0f);
        }
        acc += (a0 + a1) + (a2 + a3);
    }

    // wave64 shuffle reduce, then cross-wave via LDS
    for (int o = 32; o; o >>= 1) acc += __shfl_down(acc, o, 64);
    if ((tid & 63) == 0) wsum[tid >> 6] = acc;
    __syncthreads();
    if (tid == 0) {
        float tot = (wsum[0] + wsum[1]) + (wsum[2] + wsum[3]);
        float np  = (float)npos * (float)nneg;
        per_sample[b] = (np > 0.0f) ? (tot / np) : 0.0f;
    }
}

__global__ __launch_bounds__(256) void rerank_reduce(
    const float* __restrict__ per_sample,
    float*       __restrict__ out,
    int n)
{
    __shared__ float wsum[4];
    const int tid = threadIdx.x;
    float acc = 0.0f;
    for (int i = tid; i < n; i += 256) acc += per_sample[i];
    for (int o = 32; o; o >>= 1) acc += __shfl_down(acc, o, 64);
    if ((tid & 63) == 0) wsum[tid >> 6] = acc;
    __syncthreads();
    if (tid == 0) out[0] = ((wsum[0] + wsum[1]) + (wsum[2] + wsum[3])) / (float)n;
}

extern "C" void kernel_launch(void* const* d_in, const int* in_sizes, int n_in,
                              void* d_out, int out_size, void* d_ws, size_t ws_size,
                              hipStream_t stream)
{
    const float* scores = (const float*)d_in[0];
    const int*   labels = (const int*)d_in[1];
    float*       out    = (float*)d_out;
    float*       ws     = (float*)d_ws;   // B floats of scratch

    const int B = in_sizes[0] / L;

    rerank_per_sample<<<B, 256, 0, stream>>>(scores, labels, ws);
    rerank_reduce<<<1, 256, 0, stream>>>(ws, out, B);
}

// Round 2
// 14.149 us; speedup vs baseline: 1.2826x; 1.2826x over previous
//
#include <hip/hip_runtime.h>

// RerankLoss: margin-ranking hinge over all pos-neg pairs per row.
// scores: [B, L] f32, labels: [B, L] i32 in {0,1}; output: scalar f32.
// out = (1/B) * sum_b [ sum_{i pos, j neg} relu(1 - (s_i - s_j)) / (n_pos*n_neg) ]
//
// Structure: one wave (64 thr) per sample. Ballot-compact positives/negatives
// into LDS (order-free, no atomics), then each lane owns positives i = lane,
// lane+64, ... and sweeps negatives as float4 LDS broadcasts.

constexpr int L  = 200;
constexpr int LQ = L / 4;           // 50 quads per row
constexpr float MARGIN = 1.0f;

__global__ __launch_bounds__(64) void rerank_per_sample(
    const float* __restrict__ scores,
    const int*   __restrict__ labels,
    float*       __restrict__ per_sample)
{
    __shared__ float posv[L + 8];
    __shared__ float negv[L + 8];

    const int b    = blockIdx.x;
    const int lane = threadIdx.x;

    // --- coalesced vector load: lanes 0..49 hold 4 consecutive elements ---
    float4 sv = make_float4(0.f, 0.f, 0.f, 0.f);
    int4   lv = make_int4(0, 0, 0, 0);
    const bool act = lane < LQ;
    if (act) {
        sv = ((const float4*)(scores + (long)b * L))[lane];
        lv = ((const int4*)(labels + (long)b * L))[lane];
    }
    const float ev[4] = {sv.x, sv.y, sv.z, sv.w};
    const int   lb[4] = {lv.x, lv.y, lv.z, lv.w};

    // --- ballot compaction: unique LDS slot = base + popc(mask & lower) ---
    const unsigned long long lower = (1ull << lane) - 1ull;
    int npos = 0, nneg = 0;
#pragma unroll
    for (int j = 0; j < 4; ++j) {
        const bool isp = act && (lb[j] != 0);
        const bool isn = act && (lb[j] == 0);
        const unsigned long long mp = __ballot(isp);
        const unsigned long long mn = __ballot(isn);
        if (isp) posv[npos + __popcll(mp & lower)] = ev[j];
        if (isn) negv[nneg + __popcll(mn & lower)] = ev[j];
        npos += __popcll(mp);      // wave-uniform
        nneg += __popcll(mn);
    }

    // pad negatives to a multiple of 4; relu(c - 3e38) == 0 kills pad terms
    const int nneg4 = (nneg + 3) & ~3;
    if (lane < nneg4 - nneg) negv[nneg + lane] = -3.0e38f;
    __syncthreads();               // 1-wave block: compiles to lgkmcnt drain

    // --- pair loop: lane owns positive i; negatives via LDS broadcast ---
    float acc = 0.0f;
    const float4* nv = (const float4*)negv;
    const int nq = nneg4 >> 2;
    for (int i = lane; i < npos; i += 64) {
        const float c = MARGIN - posv[i];
        float a0 = 0.f, a1 = 0.f, a2 = 0.f, a3 = 0.f;
        for (int j = 0; j < nq; ++j) {
            float4 n = nv[j];
            a0 += fmaxf(c + n.x, 0.0f);
            a1 += fmaxf(c + n.y, 0.0f);
            a2 += fmaxf(c + n.z, 0.0f);
            a3 += fmaxf(c + n.w, 0.0f);
        }
        acc += (a0 + a1) + (a2 + a3);
    }

    // wave64 reduce
    for (int o = 32; o; o >>= 1) acc += __shfl_down(acc, o, 64);
    if (lane == 0) {
        const float np = (float)npos * (float)nneg;
        per_sample[b] = (np > 0.0f) ? (acc / np) : 0.0f;
    }
}

__global__ __launch_bounds__(256) void rerank_reduce(
    const float* __restrict__ per_sample,
    float*       __restrict__ out,
    int n)
{
    __shared__ float wsum[4];
    const int tid = threadIdx.x;
    float acc = 0.0f;
    const float4* pv = (const float4*)per_sample;
    for (int i = tid; i < (n >> 2); i += 256) {
        float4 v = pv[i];
        acc += (v.x + v.y) + (v.z + v.w);
    }
    for (int o = 32; o; o >>= 1) acc += __shfl_down(acc, o, 64);
    if ((tid & 63) == 0) wsum[tid >> 6] = acc;
    __syncthreads();
    if (tid == 0) out[0] = ((wsum[0] + wsum[1]) + (wsum[2] + wsum[3])) / (float)n;
}

extern "C" void kernel_launch(void* const* d_in, const int* in_sizes, int n_in,
                              void* d_out, int out_size, void* d_ws, size_t ws_size,
                              hipStream_t stream)
{
    const float* scores = (const float*)d_in[0];
    const int*   labels = (const int*)d_in[1];
    float*       out    = (float*)d_out;
    float*       ws     = (float*)d_ws;   // B floats of scratch

    const int B = in_sizes[0] / L;

    rerank_per_sample<<<B, 64, 0, stream>>>(scores, labels, ws);
    rerank_reduce<<<1, 256, 0, stream>>>(ws, out, B);
}